// Round 2
// baseline (1189.325 us; speedup 1.0000x reference)
//
#include <hip/hip_runtime.h>

// FirstOrderCondRNN, two-phase split:
//   Phase A (rnn_dyn_kernel, 48 blocks): sequential r-dynamics. Keeps W/wt in
//     registers (needed for I_mbon) but stores only r_all / ro_all (~2.3 MB).
//   Phase B (plasticity_kernel, 960 blocks): per (b,d) row, re-derives the DAN
//     trace from r_all (stream-ordered after A), replays the elementwise wt/W
//     recurrence, and streams the 743 MB W/wt history at full occupancy with
//     coalesced non-temporal float4 stores.

#define NB   48
#define NK   800
#define NM   20
#define NF   60
#define NE   2
#define TT   121
#define NR   100
#define ND   20
#define NSTEP 120
#define SLAB (NB * NM * NK)   // 768000 floats per history timestep

#define R_OFF   0
#define W_OFF   580800      // 121*48*100
#define WT_OFF  93508800    // + 121*48*20*800
#define RO_OFF  186436800   // + 121*48*20*800

typedef float f4 __attribute__((ext_vector_type(4)));

// ---------------------------------------------------------------- Phase A ---
__global__ __launch_bounds__(640)
void rnn_dyn_kernel(const float* __restrict__ r_kc,
                    const float* __restrict__ r_ext,
                    const float* __restrict__ timev,
                    const float* __restrict__ W_kc0,
                    const float* __restrict__ wt0,
                    const float* __restrict__ W_recur,
                    const float* __restrict__ W_readout,
                    const float* __restrict__ bias,
                    const float* __restrict__ W_ext,
                    float* __restrict__ out)
{
    const int b   = blockIdx.x;
    const int tid = threadIdx.x;
    const int d   = tid >> 5;   // 0..19 (row of W for this thread)
    const int kg  = tid & 31;   // 0..31 (column group)

    __shared__ __align__(16) float Wr_sh[NR * NR];   // 40 KB, DAN cols zeroed
    __shared__ __align__(16) float rkc_sh[NK];
    __shared__ __align__(16) float vsh[NK];          // rb_kc trace
    __shared__ float rsh[NR];
    __shared__ float rnew_sh[NR];
    __shared__ float bias_sh[NR];
    __shared__ float Imbon_sh[NM];
    __shared__ float rbdan_sh[ND];
    __shared__ float rdan_sh[ND];
    __shared__ float Wro_sh[NM];

    const float dt  = timev[1] - timev[0];   // 0.5
    const float dtw = dt * 0.2f;             // dt / TAU_W
    const float dtr = dt;                    // dt / TAU_R (TAU_R = 1)

    // ---- init: stage Wr (with [:NM, -ND:] = 0 patch), bias, readout ----
    for (int idx = tid; idx < NR * NR; idx += 640) {
        int i = idx / NR, j = idx - i * NR;
        float w = W_recur[idx];
        if (i < NM && j >= NR - ND) w = 0.f;
        Wr_sh[idx] = w;
    }
    if (tid < NR) {
        bias_sh[tid] = bias[tid];
        float r0 = (tid < NM) ? 0.f : 0.1f;
        rsh[tid] = r0;
        out[R_OFF + (size_t)b * NR + tid] = r0;   // r_all[0]
    }
    if (tid < NM) { Wro_sh[tid] = W_readout[tid]; rbdan_sh[tid] = 0.1f; }
    if (tid == 0) out[RO_OFF + b] = 0.f;          // ro_all[0] (r0 mbon = 0)

    // ---- load W/wt state into registers (history stores moved to phase B) --
    float4 Wv[7], wtv[7], uv[7];
    const size_t rowbase = ((size_t)b * NM + d) * NK;
    #pragma unroll
    for (int j = 0; j < 7; ++j) {
        int k0 = 4 * kg + 128 * j;
        if (k0 < NK) {
            Wv[j]  = *(const float4*)(W_kc0 + rowbase + k0);
            wtv[j] = *(const float4*)(wt0   + rowbase + k0);
        }
    }
    __syncthreads();

    for (int t = 0; t < NSTEP; ++t) {
        // S0: stage rkc column (strided input: t innermost), update rb_kc
        for (int k = tid; k < NK; k += 640) {
            float u = r_kc[((size_t)b * NK + k) * TT + t];
            rkc_sh[k] = u;
            float vold = (t == 0) ? u : vsh[k];
            vsh[k] = vold + (u - vold) * dtw;
        }
        __syncthreads();

        // S1: I_mbon = sum_k W[d,k]*u[k]  (per-thread dot + 32-lane butterfly)
        float partial = 0.f;
        #pragma unroll
        for (int j = 0; j < 7; ++j) {
            int k0 = 4 * kg + 128 * j;
            if (k0 < NK) {
                uv[j] = *(const float4*)&rkc_sh[k0];
                partial += Wv[j].x * uv[j].x + Wv[j].y * uv[j].y
                         + Wv[j].z * uv[j].z + Wv[j].w * uv[j].w;
            }
        }
        partial += __shfl_xor(partial, 1);
        partial += __shfl_xor(partial, 2);
        partial += __shfl_xor(partial, 4);
        partial += __shfl_xor(partial, 8);
        partial += __shfl_xor(partial, 16);
        if (kg == 0) Imbon_sh[d] = partial;

        // Wr_prod[i] = sum_j r[j]*Wr[i,j], 4 lanes per row
        float wp = 0.f;
        if (tid < 4 * NR) {
            int i = tid >> 2, jg = tid & 3;
            const float* wr = Wr_sh + i * NR + jg * 25;
            const float* rr = rsh + jg * 25;
            #pragma unroll
            for (int j = 0; j < 25; ++j) wp += rr[j] * wr[j];
            wp += __shfl_xor(wp, 1);
            wp += __shfl_xor(wp, 2);
        }
        __syncthreads();

        // S2: r_new
        if (tid < 4 * NR && (tid & 3) == 0) {
            int i = tid >> 2;
            float Itot;
            if (i < NM) {
                Itot = Imbon_sh[i];
            } else if (i < NM + NF) {
                float e0 = r_ext[((size_t)b * NE + 0) * TT + t];
                float e1 = r_ext[((size_t)b * NE + 1) * TT + t];
                Itot = e0 * W_ext[(i - NM) * NE + 0] + e1 * W_ext[(i - NM) * NE + 1];
            } else {
                Itot = 0.f;
            }
            float act = fmaxf(wp + bias_sh[i] + Itot, 0.f);
            float rn  = rsh[i] + (act - rsh[i]) * dtr;
            rnew_sh[i] = rn;
            out[R_OFF + ((size_t)(t + 1) * NB + b) * NR + i] = rn;
        }
        __syncthreads();

        // S3: dan traces, r copy, readout
        if (tid < ND) {
            float rd = rnew_sh[NR - ND + tid];
            rdan_sh[tid] = rd;
            rbdan_sh[tid] += (rd - rbdan_sh[tid]) * dtw;
        }
        if (tid >= 128 && tid < 128 + NR) rsh[tid - 128] = rnew_sh[tid - 128];
        if (tid == 64) {
            float ro = 0.f;
            #pragma unroll
            for (int m = 0; m < NM; ++m) ro += rnew_sh[m] * Wro_sh[m];
            out[RO_OFF + (size_t)(t + 1) * NB + b] = ro;
        }
        __syncthreads();

        // S4: plasticity register update (needed for I_mbon); no stores
        float a = rbdan_sh[d];
        float c = rdan_sh[d];
        #pragma unroll
        for (int j = 0; j < 7; ++j) {
            int k0 = 4 * kg + 128 * j;
            if (k0 < NK) {
                float4 v4 = *(const float4*)&vsh[k0];
                wtv[j].x += dt * (a * uv[j].x - c * v4.x);
                wtv[j].y += dt * (a * uv[j].y - c * v4.y);
                wtv[j].z += dt * (a * uv[j].z - c * v4.z);
                wtv[j].w += dt * (a * uv[j].w - c * v4.w);
                Wv[j].x = fminf(fmaxf(Wv[j].x + (wtv[j].x - Wv[j].x) * dtw, 0.f), 0.05f);
                Wv[j].y = fminf(fmaxf(Wv[j].y + (wtv[j].y - Wv[j].y) * dtw, 0.f), 0.05f);
                Wv[j].z = fminf(fmaxf(Wv[j].z + (wtv[j].z - Wv[j].z) * dtw, 0.f), 0.05f);
                Wv[j].w = fminf(fmaxf(Wv[j].w + (wtv[j].w - Wv[j].w) * dtw, 0.f), 0.05f);
            }
        }
        __syncthreads();  // protect vsh/rkc_sh against next S0
    }
}

// ---------------------------------------------------------------- Phase B ---
// One block per (b,d) row: 960 blocks x 256 threads. Thread tid<200 owns the
// float4 chunk k0=4*tid of W[b,d,:]/wt[b,d,:]. c[t] comes from r_all (written
// by phase A); a[t] is the identical sequential EMA; v is recomputed from the
// input spikes. History streamed with non-temporal coalesced float4 stores.
__global__ __launch_bounds__(256)
void plasticity_kernel(const float* __restrict__ r_kc,
                       const float* __restrict__ timev,
                       const float* __restrict__ W_kc0,
                       const float* __restrict__ wt0,
                       float* out)
{
    const int bd  = blockIdx.x;           // b*NM + d
    const int b   = bd / NM;
    const int d   = bd - b * NM;
    const int tid = threadIdx.x;

    __shared__ float a_sh[NSTEP];
    __shared__ float c_sh[NSTEP];
    __shared__ __align__(16) float u_sh[8][NK + 4];   // +4 pad, 25.7 KB

    const float dt  = timev[1] - timev[0];
    const float dtw = dt * 0.2f;

    // DAN rate trace for this (b,d): c[t] = r_all[t+1, b, NR-ND+d]
    if (tid < NSTEP)
        c_sh[tid] = out[R_OFF + ((size_t)(tid + 1) * NB + b) * NR + (NR - ND + d)];
    __syncthreads();
    if (tid == 0) {   // sequential EMA, identical op order to phase A
        float a = 0.1f;
        for (int t = 0; t < NSTEP; ++t) { a += (c_sh[t] - a) * dtw; a_sh[t] = a; }
    }

    const size_t rowbase = ((size_t)b * NM + d) * NK;
    const int  k0  = 4 * tid;
    const bool act = (k0 < NK);           // tid < 200
    f4 Wv = {0.f, 0.f, 0.f, 0.f}, wtv = Wv, v4 = Wv;
    if (act) {
        Wv  = *(const f4*)(W_kc0 + rowbase + k0);
        wtv = *(const f4*)(wt0   + rowbase + k0);
        __builtin_nontemporal_store(Wv,  (f4*)(out + W_OFF  + rowbase + k0));  // t=0 slab
        __builtin_nontemporal_store(wtv, (f4*)(out + WT_OFF + rowbase + k0));
    }
    __syncthreads();   // a_sh ready

    const float* ub = r_kc + (size_t)b * NK * TT;

    for (int ch = 0; ch < NSTEP / 8; ++ch) {
        const int t0 = 8 * ch;
        // stage u[b, 0:800, t0:t0+8] -> u_sh[tt][k]  (32-B segments per k-row)
        #pragma unroll
        for (int it = 0; it < (NK * 8) / 256; ++it) {
            int idx = tid + 256 * it;
            int k = idx >> 3, tt = idx & 7;
            u_sh[tt][k] = ub[(size_t)k * TT + t0 + tt];
        }
        __syncthreads();

        if (act) {
            #pragma unroll
            for (int tt = 0; tt < 8; ++tt) {
                const int t = t0 + tt;
                f4 u4 = *(const f4*)&u_sh[tt][k0];
                if (t == 0) {
                    v4 = u4;                       // rb_kc[0] = u[0] after EMA
                } else {
                    v4.x += (u4.x - v4.x) * dtw;
                    v4.y += (u4.y - v4.y) * dtw;
                    v4.z += (u4.z - v4.z) * dtw;
                    v4.w += (u4.w - v4.w) * dtw;
                }
                const float a = a_sh[t];
                const float c = c_sh[t];
                wtv.x += dt * (a * u4.x - c * v4.x);
                wtv.y += dt * (a * u4.y - c * v4.y);
                wtv.z += dt * (a * u4.z - c * v4.z);
                wtv.w += dt * (a * u4.w - c * v4.w);
                Wv.x = fminf(fmaxf(Wv.x + (wtv.x - Wv.x) * dtw, 0.f), 0.05f);
                Wv.y = fminf(fmaxf(Wv.y + (wtv.y - Wv.y) * dtw, 0.f), 0.05f);
                Wv.z = fminf(fmaxf(Wv.z + (wtv.z - Wv.z) * dtw, 0.f), 0.05f);
                Wv.w = fminf(fmaxf(Wv.w + (wtv.w - Wv.w) * dtw, 0.f), 0.05f);
                const size_t slab = (size_t)(t + 1) * SLAB;
                __builtin_nontemporal_store(Wv,  (f4*)(out + W_OFF  + slab + rowbase + k0));
                __builtin_nontemporal_store(wtv, (f4*)(out + WT_OFF + slab + rowbase + k0));
            }
        }
        __syncthreads();   // protect u_sh before next stage
    }
}

extern "C" void kernel_launch(void* const* d_in, const int* in_sizes, int n_in,
                              void* d_out, int out_size, void* d_ws, size_t ws_size,
                              hipStream_t stream) {
    const float* r_kc      = (const float*)d_in[0];
    const float* r_ext     = (const float*)d_in[1];
    const float* timev     = (const float*)d_in[2];
    const float* W_kc0     = (const float*)d_in[3];
    const float* wt0       = (const float*)d_in[4];
    const float* W_recur   = (const float*)d_in[5];
    const float* W_readout = (const float*)d_in[6];
    const float* bias      = (const float*)d_in[7];
    const float* W_ext     = (const float*)d_in[8];
    float* out = (float*)d_out;

    rnn_dyn_kernel<<<dim3(NB), dim3(640), 0, stream>>>(
        r_kc, r_ext, timev, W_kc0, wt0, W_recur, W_readout, bias, W_ext, out);
    // stream-ordered: phase B reads r_all written by phase A
    plasticity_kernel<<<dim3(NB * NM), dim3(256), 0, stream>>>(
        r_kc, timev, W_kc0, wt0, out);
}

// Round 3
// 1104.409 us; speedup vs baseline: 1.0769x; 1.0769x over previous
//
#include <hip/hip_runtime.h>

// FirstOrderCondRNN, two-phase split, phase-A critical path shortened:
//   Phase A (rnn_dyn_kernel, 48 blocks x 640): sequential r-dynamics with W/wt
//     in registers. v-trace (rb_kc) and rb_dan privatized to registers;
//     r double-buffered in LDS; r_kc staged 8 steps at a time (coalesced).
//     2 barriers/step + 1 per 8 steps (was 5/step). Stores only r_all/ro_all.
//   Phase B (plasticity_kernel, 960 blocks x 256): per (b,d) row, re-derives
//     the DAN trace from r_all (stream-ordered), replays the elementwise wt/W
//     recurrence, streams the 743 MB W/wt history with NT float4 stores.

#define NB   48
#define NK   800
#define NM   20
#define NF   60
#define NE   2
#define TT   121
#define NR   100
#define ND   20
#define NSTEP 120
#define SLAB (NB * NM * NK)   // 768000 floats per history timestep

#define R_OFF   0
#define W_OFF   580800      // 121*48*100
#define WT_OFF  93508800    // + 121*48*20*800
#define RO_OFF  186436800   // + 121*48*20*800

#define WRS  101            // Wr_sh row stride (bank spread for wp loop)
#define UPAD 804            // ubuf row stride (16B-aligned)

typedef float f4 __attribute__((ext_vector_type(4)));

// ---------------------------------------------------------------- Phase A ---
__global__ __launch_bounds__(640)
void rnn_dyn_kernel(const float* __restrict__ r_kc,
                    const float* __restrict__ r_ext,
                    const float* __restrict__ timev,
                    const float* __restrict__ W_kc0,
                    const float* __restrict__ wt0,
                    const float* __restrict__ W_recur,
                    const float* __restrict__ W_readout,
                    const float* __restrict__ bias,
                    const float* __restrict__ W_ext,
                    float* __restrict__ out)
{
    const int b   = blockIdx.x;
    const int tid = threadIdx.x;
    const int d   = tid >> 5;   // 0..19 (row of W for this thread)
    const int kg  = tid & 31;   // 0..31 (column group)

    __shared__ __align__(16) float Wr_sh[NR * WRS];   // 40.4 KB, DAN cols zeroed
    __shared__ __align__(16) float ubuf[8][UPAD];     // 25.7 KB, 8-step u stage
    __shared__ float rsh[2][NR];                      // double-buffered rates
    __shared__ float bias_sh[NR];
    __shared__ float Imbon_sh[NM];
    __shared__ float rext_sh[NE][TT];
    __shared__ float Wext_sh[NF * NE];
    __shared__ float Wro_sh[NM];

    const float dt  = timev[1] - timev[0];   // 0.5
    const float dtw = dt * 0.2f;             // dt / TAU_W
    const float dtr = dt;                    // dt / TAU_R (TAU_R = 1)

    // ---- init: stage Wr (with [:NM, -ND:] = 0 patch), bias, rext, readout --
    for (int idx = tid; idx < NR * NR; idx += 640) {
        int i = idx / NR, j = idx - i * NR;
        float w = W_recur[idx];
        if (i < NM && j >= NR - ND) w = 0.f;
        Wr_sh[i * WRS + j] = w;
    }
    for (int idx = tid; idx < NE * TT; idx += 640) {
        int e = idx / TT, s = idx - e * TT;
        rext_sh[e][s] = r_ext[((size_t)b * NE + e) * TT + s];
    }
    if (tid < NF * NE) Wext_sh[tid] = W_ext[tid];
    if (tid < NR) {
        bias_sh[tid] = bias[tid];
        float r0 = (tid < NM) ? 0.f : 0.1f;
        rsh[0][tid] = r0;
        out[R_OFF + (size_t)b * NR + tid] = r0;   // r_all[0]
    }
    if (tid < NM) Wro_sh[tid] = W_readout[tid];
    if (tid == 0) out[RO_OFF + b] = 0.f;          // ro_all[0] (r0 mbon = 0)

    // ---- W/wt state in registers; v-trace + rb_dan privatized ----
    float4 Wv[7], wtv[7], uv[7], vv[7];
    float rbdan = 0.1f;
    const size_t rowbase = ((size_t)b * NM + d) * NK;
    #pragma unroll
    for (int j = 0; j < 7; ++j) {
        int k0 = 4 * kg + 128 * j;
        vv[j] = (float4){0.f, 0.f, 0.f, 0.f};
        if (k0 < NK) {
            Wv[j]  = *(const float4*)(W_kc0 + rowbase + k0);
            wtv[j] = *(const float4*)(wt0   + rowbase + k0);
        }
    }
    __syncthreads();

    const float* ub = r_kc + (size_t)b * NK * TT;

    for (int ch = 0; ch < NSTEP / 8; ++ch) {
        const int t0 = 8 * ch;
        // STAGE: u[b, :, t0:t0+8] -> ubuf[tt][k]  (coalesced 32-B runs)
        #pragma unroll
        for (int it = 0; it < (NK * 8) / 640; ++it) {
            int idx = tid + 640 * it;
            int k = idx >> 3, tt = idx & 7;
            ubuf[tt][k] = ub[(size_t)k * TT + t0 + tt];
        }
        __syncthreads();   // ubuf visible (also fences prior step's LDS reads)

        #pragma unroll
        for (int tt = 0; tt < 8; ++tt) {
            const int t   = t0 + tt;
            const int cur = t & 1, nxt = cur ^ 1;

            // S1: uv load + v EMA + I_mbon dot (32-lane butterfly) + Wr_prod
            float partial = 0.f;
            #pragma unroll
            for (int j = 0; j < 7; ++j) {
                int k0 = 4 * kg + 128 * j;
                if (k0 < NK) {
                    uv[j] = *(const float4*)&ubuf[tt][k0];
                    if (t == 0) {
                        vv[j] = uv[j];
                    } else {
                        vv[j].x += (uv[j].x - vv[j].x) * dtw;
                        vv[j].y += (uv[j].y - vv[j].y) * dtw;
                        vv[j].z += (uv[j].z - vv[j].z) * dtw;
                        vv[j].w += (uv[j].w - vv[j].w) * dtw;
                    }
                    partial += Wv[j].x * uv[j].x + Wv[j].y * uv[j].y
                             + Wv[j].z * uv[j].z + Wv[j].w * uv[j].w;
                }
            }
            partial += __shfl_xor(partial, 1);
            partial += __shfl_xor(partial, 2);
            partial += __shfl_xor(partial, 4);
            partial += __shfl_xor(partial, 8);
            partial += __shfl_xor(partial, 16);
            if (kg == 0) Imbon_sh[d] = partial;

            // Wr_prod[i] = sum_j r[j]*Wr[i,j], 4 lanes per row
            float wp = 0.f;
            if (tid < 4 * NR) {
                int i = tid >> 2, jg = tid & 3;
                const float* wr = Wr_sh + i * WRS + jg * 25;
                const float* rr = &rsh[cur][jg * 25];
                #pragma unroll
                for (int j = 0; j < 25; ++j) wp += rr[j] * wr[j];
                wp += __shfl_xor(wp, 1);
                wp += __shfl_xor(wp, 2);
            }
            __syncthreads();   // B2: Imbon_sh visible

            // S2: r_new -> rsh[nxt] + r_all store
            if (tid < 4 * NR && (tid & 3) == 0) {
                int i = tid >> 2;
                float Itot;
                if (i < NM) {
                    Itot = Imbon_sh[i];
                } else if (i < NM + NF) {
                    Itot = rext_sh[0][t] * Wext_sh[(i - NM) * NE + 0]
                         + rext_sh[1][t] * Wext_sh[(i - NM) * NE + 1];
                } else {
                    Itot = 0.f;
                }
                float act = fmaxf(wp + bias_sh[i] + Itot, 0.f);
                float rn  = rsh[cur][i] + (act - rsh[cur][i]) * dtr;
                rsh[nxt][i] = rn;
                out[R_OFF + ((size_t)(t + 1) * NB + b) * NR + i] = rn;
            }
            __syncthreads();   // B3: r_new visible

            // S4: private rb_dan EMA + plasticity register update; readout
            float c = rsh[nxt][NR - ND + d];
            rbdan += (c - rbdan) * dtw;
            float a = rbdan;
            #pragma unroll
            for (int j = 0; j < 7; ++j) {
                int k0 = 4 * kg + 128 * j;
                if (k0 < NK) {
                    wtv[j].x += dt * (a * uv[j].x - c * vv[j].x);
                    wtv[j].y += dt * (a * uv[j].y - c * vv[j].y);
                    wtv[j].z += dt * (a * uv[j].z - c * vv[j].z);
                    wtv[j].w += dt * (a * uv[j].w - c * vv[j].w);
                    Wv[j].x = fminf(fmaxf(Wv[j].x + (wtv[j].x - Wv[j].x) * dtw, 0.f), 0.05f);
                    Wv[j].y = fminf(fmaxf(Wv[j].y + (wtv[j].y - Wv[j].y) * dtw, 0.f), 0.05f);
                    Wv[j].z = fminf(fmaxf(Wv[j].z + (wtv[j].z - Wv[j].z) * dtw, 0.f), 0.05f);
                    Wv[j].w = fminf(fmaxf(Wv[j].w + (wtv[j].w - Wv[j].w) * dtw, 0.f), 0.05f);
                }
            }
            if (tid == 64) {
                float ro = 0.f;
                #pragma unroll
                for (int m = 0; m < NM; ++m) ro += rsh[nxt][m] * Wro_sh[m];
                out[RO_OFF + (size_t)(t + 1) * NB + b] = ro;
            }
            // no barrier: next S1/STAGE touches ubuf (fenced at chunk head),
            // rsh[cur] is written only two steps later (two barriers away).
        }
    }
}

// ---------------------------------------------------------------- Phase B ---
// One block per (b,d) row: 960 blocks x 256 threads. Thread tid<200 owns the
// float4 chunk k0=4*tid of W[b,d,:]/wt[b,d,:]. c[t] comes from r_all (written
// by phase A); a[t] is the identical sequential EMA; v is recomputed from the
// input spikes. History streamed with non-temporal coalesced float4 stores.
__global__ __launch_bounds__(256)
void plasticity_kernel(const float* __restrict__ r_kc,
                       const float* __restrict__ timev,
                       const float* __restrict__ W_kc0,
                       const float* __restrict__ wt0,
                       float* out)
{
    const int bd  = blockIdx.x;           // b*NM + d
    const int b   = bd / NM;
    const int d   = bd - b * NM;
    const int tid = threadIdx.x;

    __shared__ float a_sh[NSTEP];
    __shared__ float c_sh[NSTEP];
    __shared__ __align__(16) float u_sh[8][NK + 4];   // +4 pad, 25.7 KB

    const float dt  = timev[1] - timev[0];
    const float dtw = dt * 0.2f;

    // DAN rate trace for this (b,d): c[t] = r_all[t+1, b, NR-ND+d]
    if (tid < NSTEP)
        c_sh[tid] = out[R_OFF + ((size_t)(tid + 1) * NB + b) * NR + (NR - ND + d)];
    __syncthreads();
    if (tid == 0) {   // sequential EMA, identical op order to phase A
        float a = 0.1f;
        for (int t = 0; t < NSTEP; ++t) { a += (c_sh[t] - a) * dtw; a_sh[t] = a; }
    }

    const size_t rowbase = ((size_t)b * NM + d) * NK;
    const int  k0  = 4 * tid;
    const bool act = (k0 < NK);           // tid < 200
    f4 Wv = {0.f, 0.f, 0.f, 0.f}, wtv = Wv, v4 = Wv;
    if (act) {
        Wv  = *(const f4*)(W_kc0 + rowbase + k0);
        wtv = *(const f4*)(wt0   + rowbase + k0);
        __builtin_nontemporal_store(Wv,  (f4*)(out + W_OFF  + rowbase + k0));  // t=0 slab
        __builtin_nontemporal_store(wtv, (f4*)(out + WT_OFF + rowbase + k0));
    }
    __syncthreads();   // a_sh ready

    const float* ub = r_kc + (size_t)b * NK * TT;

    for (int ch = 0; ch < NSTEP / 8; ++ch) {
        const int t0 = 8 * ch;
        // stage u[b, 0:800, t0:t0+8] -> u_sh[tt][k]  (32-B segments per k-row)
        #pragma unroll
        for (int it = 0; it < (NK * 8) / 256; ++it) {
            int idx = tid + 256 * it;
            int k = idx >> 3, tt = idx & 7;
            u_sh[tt][k] = ub[(size_t)k * TT + t0 + tt];
        }
        __syncthreads();

        if (act) {
            #pragma unroll
            for (int tt = 0; tt < 8; ++tt) {
                const int t = t0 + tt;
                f4 u4 = *(const f4*)&u_sh[tt][k0];
                if (t == 0) {
                    v4 = u4;                       // rb_kc[0] = u[0] after EMA
                } else {
                    v4.x += (u4.x - v4.x) * dtw;
                    v4.y += (u4.y - v4.y) * dtw;
                    v4.z += (u4.z - v4.z) * dtw;
                    v4.w += (u4.w - v4.w) * dtw;
                }
                const float a = a_sh[t];
                const float c = c_sh[t];
                wtv.x += dt * (a * u4.x - c * v4.x);
                wtv.y += dt * (a * u4.y - c * v4.y);
                wtv.z += dt * (a * u4.z - c * v4.z);
                wtv.w += dt * (a * u4.w - c * v4.w);
                Wv.x = fminf(fmaxf(Wv.x + (wtv.x - Wv.x) * dtw, 0.f), 0.05f);
                Wv.y = fminf(fmaxf(Wv.y + (wtv.y - Wv.y) * dtw, 0.f), 0.05f);
                Wv.z = fminf(fmaxf(Wv.z + (wtv.z - Wv.z) * dtw, 0.f), 0.05f);
                Wv.w = fminf(fmaxf(Wv.w + (wtv.w - Wv.w) * dtw, 0.f), 0.05f);
                const size_t slab = (size_t)(t + 1) * SLAB;
                __builtin_nontemporal_store(Wv,  (f4*)(out + W_OFF  + slab + rowbase + k0));
                __builtin_nontemporal_store(wtv, (f4*)(out + WT_OFF + slab + rowbase + k0));
            }
        }
        __syncthreads();   // protect u_sh before next stage
    }
}

extern "C" void kernel_launch(void* const* d_in, const int* in_sizes, int n_in,
                              void* d_out, int out_size, void* d_ws, size_t ws_size,
                              hipStream_t stream) {
    const float* r_kc      = (const float*)d_in[0];
    const float* r_ext     = (const float*)d_in[1];
    const float* timev     = (const float*)d_in[2];
    const float* W_kc0     = (const float*)d_in[3];
    const float* wt0       = (const float*)d_in[4];
    const float* W_recur   = (const float*)d_in[5];
    const float* W_readout = (const float*)d_in[6];
    const float* bias      = (const float*)d_in[7];
    const float* W_ext     = (const float*)d_in[8];
    float* out = (float*)d_out;

    rnn_dyn_kernel<<<dim3(NB), dim3(640), 0, stream>>>(
        r_kc, r_ext, timev, W_kc0, wt0, W_recur, W_readout, bias, W_ext, out);
    // stream-ordered: phase B reads r_all written by phase A
    plasticity_kernel<<<dim3(NB * NM), dim3(256), 0, stream>>>(
        r_kc, timev, W_kc0, wt0, out);
}